// Round 16
// baseline (59.640 us; speedup 1.0000x reference)
//
#include <hip/hip_runtime.h>
#include <hip/hip_bf16.h>

#define BT 128   // B*T
#define NN 256   // nodes
#define FF 128   // features
#define HH 4     // heads
#define DD 32    // head dim
#define XC 136   // xc row stride (bf16): 272B, 16B-aligned
#define XK 136   // wt_all row stride (bf16)
#define WCS 264  // whc col stride (bf16)
#define L2E 1.4426950408889634f

typedef __attribute__((ext_vector_type(8))) short bf16x8;
typedef __attribute__((ext_vector_type(4))) float f32x4;
typedef unsigned int uint;
typedef unsigned short ushort;

__device__ __forceinline__ float elu1(float x) { return x > 0.f ? x : (__expf(x) - 1.f); }
__device__ __forceinline__ float exp2_fast(float x) {
  float r; asm("v_exp_f32 %0, %1" : "=v"(r) : "v"(x)); return r;
}
__device__ __forceinline__ ushort f2bfn(float f) {
  __hip_bfloat16 h = __float2bfloat16(f);
  return *reinterpret_cast<ushort*>(&h);
}
__device__ __forceinline__ float bf2f(ushort u) {
  union { uint u; float f; } v; v.u = ((uint)u) << 16; return v.f;
}
__device__ __forceinline__ uint pk2(float a, float b) {  // -> v_cvt_pk_bf16_f32
  return (uint)f2bfn(a) | ((uint)f2bfn(b) << 16);
}

// ONE kernel, ONE block per bt (1024 threads / 16 waves, 1 block/CU by LDS).
// All intermediates LDS-resident: xc (compact x, bf16, updated in place per
// layer), ubuf (wt_all during staging, aliased to whc4 after B-frags are in
// registers), per-head scores. No cross-block sync anywhere. LN fused at end.
__global__ __launch_bounds__(1024)
__attribute__((amdgpu_waves_per_eu(4)))
void fused_gnn(
    const float* __restrict__ xin, const int* __restrict__ mask,
    const float* __restrict__ W0, const float* __restrict__ a0,
    const float* __restrict__ W1, const float* __restrict__ a1,
    const float* __restrict__ gam, const float* __restrict__ bet,
    float* __restrict__ out) {
  __shared__ __align__(16) ushort xc[NN * XC];        // 69.6 KB compact x
  __shared__ __align__(16) ushort ubuf[HH * DD * WCS]; // 67.6 KB whc4 / wt_all
  __shared__ __align__(16) float s1s[HH][NN];         // 4 KB
  __shared__ __align__(16) float s2c[HH][NN];         // 4 KB
  __shared__ __align__(16) ushort was[HH][2][FF];     // 2 KB  W@a1, W@a2
  __shared__ int jmap[NN];
  __shared__ int rrank[NN];
  __shared__ unsigned long long balS[4];
  __shared__ int wcnt[4];

  const int bt = blockIdx.x;
  const int t = threadIdx.x;
  const int lane = t & 63;
  const int w = t >> 6;        // 0..15
  const int la = lane & 15, lg = lane >> 4;
  const int hg = w >> 2;       // head owned by this wave (0..3)
  const int wq = w & 3;        // quarter within head group

  // ================= P0: ballot + stage wt_all(W0) + was(a0) =================
  if (t < NN) {
    const int mv = mask[bt * NN + t] > 0;
    unsigned long long bal = __ballot(mv);
    if (lane == 0) { wcnt[w] = __popcll(bal); balS[w] = bal; }
  }
  {  // wt_all[n][k] = W0[k][n], all 128 cols; 16 k per thread
    const int n = t & 127;
    const int k0 = (t >> 7) * 16;
    float wv[16];
    #pragma unroll
    for (int p = 0; p < 16; ++p) wv[p] = W0[(k0 + p) * FF + n];
    uint4 q0, q1;
    q0.x = pk2(wv[0], wv[1]);  q0.y = pk2(wv[2], wv[3]);
    q0.z = pk2(wv[4], wv[5]);  q0.w = pk2(wv[6], wv[7]);
    q1.x = pk2(wv[8], wv[9]);  q1.y = pk2(wv[10], wv[11]);
    q1.z = pk2(wv[12], wv[13]); q1.w = pk2(wv[14], wv[15]);
    *(uint4*)&ubuf[n * XK + k0] = q0;
    *(uint4*)&ubuf[n * XK + k0 + 8] = q1;
  }
  if (t < 512) {  // was[hh][.][k] = W0[k][hh*32..] . a0 halves
    const int hh = t >> 7, k = t & 127;
    const float* wr = W0 + (size_t)k * FF + hh * DD;
    float wa1 = 0.f, wa2 = 0.f;
    #pragma unroll
    for (int d4 = 0; d4 < DD; d4 += 4) {
      float4 wq2 = *(const float4*)&wr[d4];
      float4 q1 = *(const float4*)&a0[d4];
      float4 q2 = *(const float4*)&a0[DD + d4];
      wa1 = fmaf(wq2.x, q1.x, fmaf(wq2.y, q1.y, fmaf(wq2.z, q1.z, fmaf(wq2.w, q1.w, wa1))));
      wa2 = fmaf(wq2.x, q2.x, fmaf(wq2.y, q2.y, fmaf(wq2.z, q2.z, fmaf(wq2.w, q2.w, wa2))));
    }
    was[hh][0][k] = f2bfn(wa1);
    was[hh][1][k] = f2bfn(wa2);
  }
  __syncthreads();  // B1: wcnt, balS, wt_all, was ready
  const int jv = wcnt[0] + wcnt[1] + wcnt[2] + wcnt[3];
  const int jv16 = (jv + 15) & ~15;
  const int ntiles = jv16 >> 4;
  const int jvp64 = (jv16 + 63) & ~63;
  const int njb = jvp64 >> 6;

  // ================= P1: ranks + B-fragment loads (W0) =================
  if (t < NN) {
    unsigned long long bal = balS[w];
    const int mv = (int)((bal >> lane) & 1ull);
    int base = 0;
    #pragma unroll
    for (int ww = 0; ww < 4; ++ww) if (ww < w) base += wcnt[ww];
    const int rk = mv ? base + __popcll(bal & ((1ull << lane) - 1ull)) : -1;
    if (mv) jmap[rk] = t;
    rrank[t] = rk;
  }
  bf16x8 bfr[2][4], bsc[4];
  #pragma unroll
  for (int ct = 0; ct < 2; ++ct)
    #pragma unroll
    for (int ks = 0; ks < 4; ++ks)
      bfr[ct][ks] = *(const bf16x8*)&ubuf[(hg * 32 + ct * 16 + la) * XK + ks * 32 + lg * 8];
  #pragma unroll
  for (int ks = 0; ks < 4; ++ks) {
    bf16x8 z = {0, 0, 0, 0, 0, 0, 0, 0};
    bsc[ks] = (la < 2) ? *(const bf16x8*)&was[hg][la][ks * 32 + lg * 8] : z;
  }
  __syncthreads();  // B2: jmap/rrank ready; all bfr loaded -> ubuf free

  // ================= P2: stage xc (compact gather) + pads =================
  {
    const int r = t >> 2;
    const int fq = (t & 3) * 32;
    if (r < jv) {
      const float* xp = xin + ((size_t)bt * NN + jmap[r]) * FF + fq;
      #pragma unroll
      for (int i = 0; i < 4; ++i) {
        float4 va = *(const float4*)&xp[i * 8];
        float4 vb = *(const float4*)&xp[i * 8 + 4];
        uint4 q;
        q.x = pk2(va.x, va.y); q.y = pk2(va.z, va.w);
        q.z = pk2(vb.x, vb.y); q.w = pk2(vb.z, vb.w);
        *(uint4*)&xc[r * XC + fq + i * 8] = q;
      }
    } else if (r < jv16) {
      const uint4 z = {0, 0, 0, 0};
      #pragma unroll
      for (int i = 0; i < 4; ++i) *(uint4*)&xc[r * XC + fq + i * 8] = z;
    }
  }
  if (t < NN && t >= jv16) {  // score pads beyond jv16 (GEMM covers [0,jv16))
    #pragma unroll
    for (int h = 0; h < HH; ++h) s2c[h][t] = -2e9f;
  }
  __syncthreads();  // B3: xc + s2c pads ready

  // ================= two layers =================
  #pragma unroll 1
  for (int L = 0; L < 2; ++L) {
    if (L == 1) {
      // restage ubuf as wt_all(W1) + was(a1)
      {
        const int n = t & 127;
        const int k0 = (t >> 7) * 16;
        float wv[16];
        #pragma unroll
        for (int p = 0; p < 16; ++p) wv[p] = W1[(k0 + p) * FF + n];
        uint4 q0, q1;
        q0.x = pk2(wv[0], wv[1]);  q0.y = pk2(wv[2], wv[3]);
        q0.z = pk2(wv[4], wv[5]);  q0.w = pk2(wv[6], wv[7]);
        q1.x = pk2(wv[8], wv[9]);  q1.y = pk2(wv[10], wv[11]);
        q1.z = pk2(wv[12], wv[13]); q1.w = pk2(wv[14], wv[15]);
        *(uint4*)&ubuf[n * XK + k0] = q0;
        *(uint4*)&ubuf[n * XK + k0 + 8] = q1;
      }
      if (t < 512) {
        const int hh = t >> 7, k = t & 127;
        const float* wr = W1 + (size_t)k * FF + hh * DD;
        float wa1 = 0.f, wa2 = 0.f;
        #pragma unroll
        for (int d4 = 0; d4 < DD; d4 += 4) {
          float4 wq2 = *(const float4*)&wr[d4];
          float4 q1 = *(const float4*)&a1[d4];
          float4 q2 = *(const float4*)&a1[DD + d4];
          wa1 = fmaf(wq2.x, q1.x, fmaf(wq2.y, q1.y, fmaf(wq2.z, q1.z, fmaf(wq2.w, q1.w, wa1))));
          wa2 = fmaf(wq2.x, q2.x, fmaf(wq2.y, q2.y, fmaf(wq2.z, q2.z, fmaf(wq2.w, q2.w, wa2))));
        }
        was[hh][0][k] = f2bfn(wa1);
        was[hh][1][k] = f2bfn(wa2);
      }
      __syncthreads();  // wt_all(W1), was(a1) ready
      #pragma unroll
      for (int ct = 0; ct < 2; ++ct)
        #pragma unroll
        for (int ks = 0; ks < 4; ++ks)
          bfr[ct][ks] = *(const bf16x8*)&ubuf[(hg * 32 + ct * 16 + la) * XK + ks * 32 + lg * 8];
      #pragma unroll
      for (int ks = 0; ks < 4; ++ks) {
        bf16x8 z = {0, 0, 0, 0, 0, 0, 0, 0};
        bsc[ks] = (la < 2) ? *(const bf16x8*)&was[hg][la][ks * 32 + lg * 8] : z;
      }
      __syncthreads();  // bfr loaded -> ubuf free for whc
    }

    // ---- GEMM phase: wave (hg,wq) computes tiles rt = wq + 4i of head hg ----
    if (t < NN && t >= jv16 && t < jvp64) {  // whc pad cols zero (ubuf now whc)
      #pragma unroll
      for (int hd = 0; hd < HH * DD; ++hd) ubuf[hd * WCS + t] = 0;
    }
    for (int rt = wq; rt < ntiles; rt += 4) {
      const int rr = rt * 16 + la;
      bf16x8 af[4];
      #pragma unroll
      for (int ks = 0; ks < 4; ++ks)
        af[ks] = *(const bf16x8*)&xc[rr * XC + ks * 32 + lg * 8];
      f32x4 acc0 = {}, acc1 = {}, accs = {};
      #pragma unroll
      for (int ks = 0; ks < 4; ++ks) {
        acc0 = __builtin_amdgcn_mfma_f32_16x16x32_bf16(af[ks], bfr[0][ks], acc0, 0, 0, 0);
        acc1 = __builtin_amdgcn_mfma_f32_16x16x32_bf16(af[ks], bfr[1][ks], acc1, 0, 0, 0);
        accs = __builtin_amdgcn_mfma_f32_16x16x32_bf16(af[ks], bsc[ks], accs, 0, 0, 0);
      }
      uint2 pa, pb;
      pa.x = pk2(acc0[0], acc0[1]); pa.y = pk2(acc0[2], acc0[3]);
      pb.x = pk2(acc1[0], acc1[1]); pb.y = pk2(acc1[2], acc1[3]);
      *(uint2*)&ubuf[(hg * 32 + la) * WCS + rt * 16 + lg * 4] = pa;
      *(uint2*)&ubuf[(hg * 32 + 16 + la) * WCS + rt * 16 + lg * 4] = pb;
      if (la < 2) {  // D col0 = s1, col1 = s2
        #pragma unroll
        for (int reg = 0; reg < 4; ++reg) {
          const int c = rt * 16 + lg * 4 + reg;
          const float v = accs[reg] * L2E;
          if (la == 0) s1s[hg][c] = v;
          else         s2c[hg][c] = (c < jv) ? v : -2e9f;
        }
      }
    }
    __syncthreads();  // whc + scores complete

    // ---- PV + epilogue (in-place xc update) ----
    float m = fmaxf(fmaxf(s2c[hg][lane], s2c[hg][64 + lane]),
                    fmaxf(s2c[hg][128 + lane], s2c[hg][192 + lane]));
    #pragma unroll
    for (int off = 32; off > 0; off >>= 1) m = fmaxf(m, __shfl_xor(m, off));
    const float s2max = m;

    for (int ti = wq; ti < ntiles; ti += 4) {
      const float s1v = s1s[hg][ti * 16 + la];
      const float tt = s1v + s2max;
      const float em = fmaxf(tt, 0.2f * tt);  // exact row max (lrelu monotone)
      f32x4 acc0 = {}, acc1 = {};
      float den = 0.f;
      for (int jb = 0; jb < njb; ++jb) {
        #pragma unroll
        for (int ks = 0; ks < 2; ++ks) {
          const int j0 = jb * 64 + ks * 32 + lg * 8;
          float4 sa = *(const float4*)&s2c[hg][j0];
          float4 sb = *(const float4*)&s2c[hg][j0 + 4];
          bf16x8 b0 = *(const bf16x8*)&ubuf[(hg * 32 + la) * WCS + j0];
          bf16x8 b1 = *(const bf16x8*)&ubuf[(hg * 32 + 16 + la) * WCS + j0];
          float t0 = s1v + sa.x, t1 = s1v + sa.y, t2 = s1v + sa.z, t3 = s1v + sa.w;
          float t4 = s1v + sb.x, t5 = s1v + sb.y, t6 = s1v + sb.z, t7 = s1v + sb.w;
          float p0 = exp2_fast(fmaxf(t0, 0.2f * t0) - em);
          float p1 = exp2_fast(fmaxf(t1, 0.2f * t1) - em);
          float p2 = exp2_fast(fmaxf(t2, 0.2f * t2) - em);
          float p3 = exp2_fast(fmaxf(t3, 0.2f * t3) - em);
          float p4 = exp2_fast(fmaxf(t4, 0.2f * t4) - em);
          float p5 = exp2_fast(fmaxf(t5, 0.2f * t5) - em);
          float p6 = exp2_fast(fmaxf(t6, 0.2f * t6) - em);
          float p7 = exp2_fast(fmaxf(t7, 0.2f * t7) - em);
          den += ((p0 + p1) + (p2 + p3)) + ((p4 + p5) + (p6 + p7));
          union { uint4 q; bf16x8 v; } u;
          u.q.x = pk2(p0, p1); u.q.y = pk2(p2, p3);
          u.q.z = pk2(p4, p5); u.q.w = pk2(p6, p7);
          acc0 = __builtin_amdgcn_mfma_f32_16x16x32_bf16(u.v, b0, acc0, 0, 0, 0);
          acc1 = __builtin_amdgcn_mfma_f32_16x16x32_bf16(u.v, b1, acc1, 0, 0, 0);
        }
      }
      den += __shfl_xor(den, 16);
      den += __shfl_xor(den, 32);
      const float inv = 1.f / den;  // compact row => p_self > 0
      #pragma unroll
      for (int reg = 0; reg < 4; ++reg) {
        const float invr = __shfl(inv, lg * 4 + reg);
        const int c2 = ti * 16 + lg * 4 + reg;
        if (c2 < jv) {
          #pragma unroll
          for (int nt = 0; nt < 2; ++nt) {
            const int f = hg * 32 + nt * 16 + la;
            const float va = nt ? acc1[reg] : acc0[reg];
            const float resid = bf2f(xc[c2 * XC + f]);
            xc[c2 * XC + f] = f2bfn(elu1(resid + va * invr));
          }
        }
      }
    }
    __syncthreads();  // xc = layer output (pads untouched, still zero)
  }

  // ================= LN + scatter (xc -> out) =================
  {
    const int node = t >> 2;
    const int fb = (t & 3) * 32;
    const int rk = rrank[node];
    float* op = out + ((size_t)bt * NN + node) * FF + fb;
    if (rk < 0) {
      const float4 z = {0.f, 0.f, 0.f, 0.f};
      #pragma unroll
      for (int i = 0; i < 8; ++i) *(float4*)&op[i * 4] = z;
    } else {
      const ushort* xr = &xc[rk * XC + fb];
      float sum = 0.f, sq = 0.f;
      #pragma unroll
      for (int i = 0; i < 4; ++i) {  // pass 1: stats (streaming)
        uint4 u = *(const uint4*)&xr[i * 8];
        const uint* pu = (const uint*)&u;
        #pragma unroll
        for (int e = 0; e < 4; ++e) {
          float f0 = bf2f((ushort)(pu[e] & 0xffffu));
          float f1 = bf2f((ushort)(pu[e] >> 16));
          sum += f0 + f1;
          sq = fmaf(f0, f0, fmaf(f1, f1, sq));
        }
      }
      sum += __shfl_xor(sum, 1); sq += __shfl_xor(sq, 1);
      sum += __shfl_xor(sum, 2); sq += __shfl_xor(sq, 2);
      const float mu = sum * (1.f / FF);
      const float var = sq * (1.f / FF) - mu * mu;
      const float rstd = rsqrtf(var + 1e-5f);
      #pragma unroll
      for (int i = 0; i < 4; ++i) {  // pass 2: reload (LDS), normalize, store
        uint4 u = *(const uint4*)&xr[i * 8];
        const uint* pu = (const uint*)&u;
        float4 g0 = *(const float4*)&gam[fb + i * 8];
        float4 g1 = *(const float4*)&gam[fb + i * 8 + 4];
        float4 b0 = *(const float4*)&bet[fb + i * 8];
        float4 b1 = *(const float4*)&bet[fb + i * 8 + 4];
        float4 o0, o1;
        o0.x = (bf2f((ushort)(pu[0] & 0xffffu)) - mu) * rstd * g0.x + b0.x;
        o0.y = (bf2f((ushort)(pu[0] >> 16))     - mu) * rstd * g0.y + b0.y;
        o0.z = (bf2f((ushort)(pu[1] & 0xffffu)) - mu) * rstd * g0.z + b0.z;
        o0.w = (bf2f((ushort)(pu[1] >> 16))     - mu) * rstd * g0.w + b0.w;
        o1.x = (bf2f((ushort)(pu[2] & 0xffffu)) - mu) * rstd * g1.x + b1.x;
        o1.y = (bf2f((ushort)(pu[2] >> 16))     - mu) * rstd * g1.y + b1.y;
        o1.z = (bf2f((ushort)(pu[3] & 0xffffu)) - mu) * rstd * g1.z + b1.z;
        o1.w = (bf2f((ushort)(pu[3] >> 16))     - mu) * rstd * g1.w + b1.w;
        *(float4*)&op[i * 8] = o0;
        *(float4*)&op[i * 8 + 4] = o1;
      }
    }
  }
}

extern "C" void kernel_launch(void* const* d_in, const int* in_sizes, int n_in,
                              void* d_out, int out_size, void* d_ws, size_t ws_size,
                              hipStream_t stream) {
  const float* xin   = (const float*)d_in[0];
  const int*   mask  = (const int*)d_in[1];
  const float* W0    = (const float*)d_in[2];
  const float* a0    = (const float*)d_in[3];
  const float* W1    = (const float*)d_in[4];
  const float* a1    = (const float*)d_in[5];
  const float* gamma = (const float*)d_in[6];
  const float* beta  = (const float*)d_in[7];

  fused_gnn<<<BT, 1024, 0, stream>>>(xin, mask, W0, a0, W1, a1,
                                     gamma, beta, (float*)d_out);
}

// Round 17
// 40.994 us; speedup vs baseline: 1.4549x; 1.4549x over previous
//
#include <hip/hip_runtime.h>
#include <hip/hip_bf16.h>

#define BT 128   // B*T
#define NN 256   // nodes
#define FF 128   // features
#define HH 4     // heads
#define DD 32    // head dim
#define XK 136   // LDS k-stride (bf16): 272B, 16B-aligned
#define WCS 264  // LDS col-stride (bf16) for whc: 528B
#define L2E 1.4426950408889634f

typedef __attribute__((ext_vector_type(8))) short bf16x8;
typedef __attribute__((ext_vector_type(4))) float f32x4;
typedef unsigned int uint;
typedef unsigned short ushort;

__device__ __forceinline__ float elu1(float x) { return x > 0.f ? x : (__expf(x) - 1.f); }
__device__ __forceinline__ float exp2_fast(float x) {
  float r; asm("v_exp_f32 %0, %1" : "=v"(r) : "v"(x)); return r;
}
__device__ __forceinline__ ushort f2bfn(float f) {
  __hip_bfloat16 h = __float2bfloat16(f);
  return *reinterpret_cast<ushort*>(&h);
}
__device__ __forceinline__ float bf2f(ushort u) {
  union { uint u; float f; } v; v.u = ((uint)u) << 16; return v.f;
}
__device__ __forceinline__ uint pk2(float a, float b) {  // -> v_cvt_pk_bf16_f32
  return (uint)f2bfn(a) | ((uint)f2bfn(b) << 16);
}

// Block = (bt, head), XCD-grouped decode (b%8 == bt>>4). 512 threads / 8 waves.
// Scores from a 3rd MFMA B-tile (col0 = W@a1, col1 = W@a2). Resid prefetched.
// T5: setprio(1) around the PV exp+MFMA cluster — the two resident blocks per
// CU are barrier-desynced, so the PV-phase block preempts the sibling's
// staging stream (m191 regime: independent blocks at different phases).
template<bool L0F>
__global__ __launch_bounds__(512)
__attribute__((amdgpu_waves_per_eu(2, 4)))
void layer_kernel(
    const float* __restrict__ xin, const ushort* __restrict__ xprev,
    const int* __restrict__ mask, const float* __restrict__ W,
    const float* __restrict__ av, ushort* __restrict__ xg,
    int* __restrict__ rrank_g) {
  __shared__ __align__(16) ushort wt[DD * XK];    // 8.7 KB
  __shared__ __align__(16) ushort whc[DD * WCS];  // 16.9 KB
  __shared__ __align__(16) ushort was[2][FF];     // 0.5 KB: bf16 W@a1, W@a2
  __shared__ __align__(16) float s1s[NN];
  __shared__ __align__(16) float s2c[NN];
  __shared__ int jmap[NN];
  __shared__ int wcnt[4];

  // XCD-grouped decode: b = (bt>>4) + 8*((bt&15) + 16*h)
  const int b = blockIdx.x;
  const int s = b >> 3;
  const int bt = (b & 7) * 16 + (s & 15);
  const int h = s >> 4;
  const int tid = threadIdx.x;
  const int lane = tid & 63;
  const int w = tid >> 6;          // 0..7
  const int la = lane & 15, lg = lane >> 4;

  // ---- early issue: W col-slice and W@a row-dots ----
  float wv[8];
  {
    const int n = tid & 31;
    const int k0 = (tid >> 5) * 8;
    #pragma unroll
    for (int p = 0; p < 8; ++p) wv[p] = W[(k0 + p) * FF + h * DD + n];
  }
  float wa1 = 0.f, wa2 = 0.f;
  if (tid < FF) {
    const float* wr = W + (size_t)tid * FF + h * DD;
    #pragma unroll
    for (int d4 = 0; d4 < DD; d4 += 4) {
      float4 wq = *(const float4*)&wr[d4];
      float4 q1 = *(const float4*)&av[d4];
      float4 q2 = *(const float4*)&av[DD + d4];
      wa1 = fmaf(wq.x, q1.x, fmaf(wq.y, q1.y, fmaf(wq.z, q1.z, fmaf(wq.w, q1.w, wa1))));
      wa2 = fmaf(wq.x, q2.x, fmaf(wq.y, q2.y, fmaf(wq.z, q2.z, fmaf(wq.w, q2.w, wa2))));
    }
  }

  // ---- ballot compaction (tid < 256) ----
  if (tid < NN) {
    const int mv = mask[bt * NN + tid] > 0;
    unsigned long long bal = __ballot(mv);
    if (lane == 0) wcnt[w] = __popcll(bal);
  }
  // stage wt[n][k] = W[k][h*32+n]
  {
    const int n = tid & 31;
    const int k0 = (tid >> 5) * 8;
    uint4 q;
    q.x = pk2(wv[0], wv[1]); q.y = pk2(wv[2], wv[3]);
    q.z = pk2(wv[4], wv[5]); q.w = pk2(wv[6], wv[7]);
    *(uint4*)&wt[n * XK + k0] = q;
  }
  if (tid < FF) { was[0][tid] = f2bfn(wa1); was[1][tid] = f2bfn(wa2); }
  __syncthreads();  // #1: wcnt, wt, was ready
  const int jv = wcnt[0] + wcnt[1] + wcnt[2] + wcnt[3];
  const int jv16 = (jv + 15) & ~15;
  const int ntiles = jv16 >> 4;
  const int jvp64 = (jv16 + 63) & ~63;
  const int njb = jvp64 >> 6;

  if (tid < NN) {
    const int mv = mask[bt * NN + tid] > 0;  // L1-hot reload
    unsigned long long bal = __ballot(mv);
    int base = 0;
    #pragma unroll
    for (int ww = 0; ww < 4; ++ww) if (ww < w) base += wcnt[ww];
    const int rk = mv ? base + __popcll(bal & ((1ull << lane) - 1ull)) : -1;
    if (mv) jmap[rk] = tid;
    if (L0F && h == 0) rrank_g[bt * NN + tid] = rk;
    if (tid >= jv) { s2c[tid] = -2e9f; s1s[tid] = 0.f; }  // pads: p=0 exactly
    if (tid >= jv16 && tid < jvp64) {
      #pragma unroll
      for (int d = 0; d < DD; ++d) whc[d * WCS + tid] = 0;
    }
  }
  // B fragments: 2 feature tiles + 1 score tile (col0=wa1, col1=wa2, rest 0)
  bf16x8 bfr[2][4], bsc[4];
  #pragma unroll
  for (int ct = 0; ct < 2; ++ct)
    #pragma unroll
    for (int ks = 0; ks < 4; ++ks)
      bfr[ct][ks] = *(const bf16x8*)&wt[(ct * 16 + la) * XK + ks * 32 + lg * 8];
  #pragma unroll
  for (int ks = 0; ks < 4; ++ks) {
    bf16x8 z = {0, 0, 0, 0, 0, 0, 0, 0};
    bsc[ks] = (la < 2) ? *(const bf16x8*)&was[la][ks * 32 + lg * 8] : z;
  }
  __syncthreads();  // #2: jmap + pads ready

  if (jv == 0) return;  // fully-masked slice: ln_scatter zero-fills via rrank

  // ---- resid prefetch (hidden under GEMM + PV) ----
  float rpre[2][2][4];
  #pragma unroll
  for (int mi = 0; mi < 2; ++mi) {
    const int ti = mi * 8 + w;
    #pragma unroll
    for (int reg = 0; reg < 4; ++reg) {
      const int c2 = ti * 16 + lg * 4 + reg;
      const int ok = (ti < ntiles) && (c2 < jv);
      const int srow = ok ? (L0F ? jmap[c2] : c2) : (L0F ? jmap[0] : 0);
      #pragma unroll
      for (int nt = 0; nt < 2; ++nt) {
        const int f = h * DD + nt * 16 + la;
        rpre[mi][nt][reg] = L0F ? xin[((size_t)bt * NN + srow) * FF + f]
                                : bf2f(xprev[((size_t)bt * NN + srow) * FF + f]);
      }
    }
  }

  // ---- GEMM: per-wave 16-row tiles; A direct from global; 3 MFMA accs ----
  for (int rt = w; rt < ntiles; rt += 8) {
    const int r = rt * 16 + la;
    const int src = (r < jv) ? (L0F ? jmap[r] : r) : 0;  // clamp: no OOB
    bf16x8 af[4];
    if (L0F) {
      const float* xp = xin + ((size_t)bt * NN + src) * FF;
      #pragma unroll
      for (int ks = 0; ks < 4; ++ks) {
        float4 v0 = *(const float4*)&xp[ks * 32 + lg * 8];
        float4 v1 = *(const float4*)&xp[ks * 32 + lg * 8 + 4];
        union { uint4 q; bf16x8 v; } u;
        u.q.x = pk2(v0.x, v0.y); u.q.y = pk2(v0.z, v0.w);
        u.q.z = pk2(v1.x, v1.y); u.q.w = pk2(v1.z, v1.w);
        af[ks] = u.v;
      }
    } else {
      const ushort* xp = xprev + ((size_t)bt * NN + src) * FF;
      #pragma unroll
      for (int ks = 0; ks < 4; ++ks)
        af[ks] = *(const bf16x8*)&xp[ks * 32 + lg * 8];
    }
    if (r >= jv) {  // zero pad rows -> whc pad cols exactly 0 (no NaN risk)
      bf16x8 zz = {0, 0, 0, 0, 0, 0, 0, 0};
      #pragma unroll
      for (int ks = 0; ks < 4; ++ks) af[ks] = zz;
    }
    f32x4 acc0 = {}, acc1 = {}, accs = {};
    #pragma unroll
    for (int ks = 0; ks < 4; ++ks) {
      acc0 = __builtin_amdgcn_mfma_f32_16x16x32_bf16(af[ks], bfr[0][ks], acc0, 0, 0, 0);
      acc1 = __builtin_amdgcn_mfma_f32_16x16x32_bf16(af[ks], bfr[1][ks], acc1, 0, 0, 0);
      accs = __builtin_amdgcn_mfma_f32_16x16x32_bf16(af[ks], bsc[ks], accs, 0, 0, 0);
    }
    {
      uint2 pa, pb;
      pa.x = pk2(acc0[0], acc0[1]); pa.y = pk2(acc0[2], acc0[3]);
      pb.x = pk2(acc1[0], acc1[1]); pb.y = pk2(acc1[2], acc1[3]);
      *(uint2*)&whc[la * WCS + rt * 16 + lg * 4] = pa;
      *(uint2*)&whc[(16 + la) * WCS + rt * 16 + lg * 4] = pb;
    }
    if (la < 2) {  // D col 0 = s1, col 1 = s2; rows = nodes lg*4+reg
      #pragma unroll
      for (int reg = 0; reg < 4; ++reg) {
        const int c = rt * 16 + lg * 4 + reg;
        const float v = accs[reg] * L2E;
        if (la == 0) s1s[c] = v;
        else         s2c[c] = (c < jv) ? v : -2e9f;
      }
    }
  }
  __syncthreads();  // #3: whc, s1s, s2c complete

  // ---- s2max: per-wave reduce over all 256 entries ----
  float m = fmaxf(fmaxf(s2c[lane], s2c[64 + lane]),
                  fmaxf(s2c[128 + lane], s2c[192 + lane]));
  #pragma unroll
  for (int off = 32; off > 0; off >>= 1) m = fmaxf(m, __shfl_xor(m, off));
  const float s2max = m;

  // ---- PV: wave w owns tiles ti = mi*8 + w (mi < 2); P in registers ----
  float s1r[2], em[2];
  #pragma unroll
  for (int mi = 0; mi < 2; ++mi) {
    float s1v = s1s[((mi * 8 + w) * 16 + la) & 255];
    s1r[mi] = s1v;
    float t = s1v + s2max;
    em[mi] = fmaxf(t, 0.2f * t);  // exact row max (lrelu monotone)
  }
  f32x4 acc[2][2] = {};
  float den[2] = {0.f, 0.f};
  __builtin_amdgcn_s_setprio(1);  // T5: favor this wave's exp+MFMA stream
  for (int jb = 0; jb < njb; ++jb) {
    #pragma unroll
    for (int ks = 0; ks < 2; ++ks) {
      const int j0 = jb * 64 + ks * 32 + lg * 8;
      float4 sa = *(const float4*)&s2c[j0];
      float4 sb = *(const float4*)&s2c[j0 + 4];
      bf16x8 b0 = *(const bf16x8*)&whc[la * WCS + j0];
      bf16x8 b1 = *(const bf16x8*)&whc[(16 + la) * WCS + j0];
      #pragma unroll
      for (int mi = 0; mi < 2; ++mi) {
        if (mi * 8 + w < ntiles) {  // wave-uniform
          const float s1v = s1r[mi], emv = em[mi];
          float t0 = s1v + sa.x, t1 = s1v + sa.y, t2 = s1v + sa.z, t3 = s1v + sa.w;
          float t4 = s1v + sb.x, t5 = s1v + sb.y, t6 = s1v + sb.z, t7 = s1v + sb.w;
          float p0 = exp2_fast(fmaxf(t0, 0.2f * t0) - emv);
          float p1 = exp2_fast(fmaxf(t1, 0.2f * t1) - emv);
          float p2 = exp2_fast(fmaxf(t2, 0.2f * t2) - emv);
          float p3 = exp2_fast(fmaxf(t3, 0.2f * t3) - emv);
          float p4 = exp2_fast(fmaxf(t4, 0.2f * t4) - emv);
          float p5 = exp2_fast(fmaxf(t5, 0.2f * t5) - emv);
          float p6 = exp2_fast(fmaxf(t6, 0.2f * t6) - emv);
          float p7 = exp2_fast(fmaxf(t7, 0.2f * t7) - emv);
          den[mi] += ((p0 + p1) + (p2 + p3)) + ((p4 + p5) + (p6 + p7));
          union { uint4 q; bf16x8 v; } u;
          u.q.x = pk2(p0, p1); u.q.y = pk2(p2, p3);
          u.q.z = pk2(p4, p5); u.q.w = pk2(p6, p7);
          acc[mi][0] = __builtin_amdgcn_mfma_f32_16x16x32_bf16(u.v, b0, acc[mi][0], 0, 0, 0);
          acc[mi][1] = __builtin_amdgcn_mfma_f32_16x16x32_bf16(u.v, b1, acc[mi][1], 0, 0, 0);
        }
      }
    }
  }
  __builtin_amdgcn_s_setprio(0);
  #pragma unroll
  for (int mi = 0; mi < 2; ++mi) {
    den[mi] += __shfl_xor(den[mi], 16);
    den[mi] += __shfl_xor(den[mi], 32);
  }

  // ---- epilogue: residual (prefetched) + ELU -> compact bf16 xg ----
  #pragma unroll
  for (int mi = 0; mi < 2; ++mi) {
    const int ti = mi * 8 + w;
    if (ti < ntiles) {
      const float inv = 1.f / den[mi];  // valid row => p_self > 0
      #pragma unroll
      for (int reg = 0; reg < 4; ++reg) {
        const float invr = __shfl(inv, lg * 4 + reg);
        const int c2 = ti * 16 + lg * 4 + reg;
        if (c2 < jv) {
          #pragma unroll
          for (int nt = 0; nt < 2; ++nt) {
            const int f = h * DD + nt * 16 + la;
            float v = elu1(rpre[mi][nt][reg] + acc[mi][nt][reg] * invr);
            xg[((size_t)bt * NN + c2) * FF + f] = f2bfn(v);
          }
        }
      }
    }
  }
}

// Block = (bt, node-quarter), XCD-grouped same as layer (b%8 == bt>>4).
__global__ __launch_bounds__(256) void ln_scatter(
    const ushort* __restrict__ xg1, const int* __restrict__ rrank_g,
    const float* __restrict__ gam, const float* __restrict__ bet,
    float* __restrict__ out) {
  const int b = blockIdx.x;
  const int bt = (b & 7) * 16 + ((b >> 3) & 15);
  const int q = b >> 7;
  const int node = q * 64 + (threadIdx.x >> 2);
  const int fb = (threadIdx.x & 3) * 32;
  const int rk = rrank_g[bt * NN + node];
  float* op = out + ((size_t)bt * NN + node) * FF + fb;
  if (rk < 0) {
    float4 z = {0.f, 0.f, 0.f, 0.f};
    #pragma unroll
    for (int i = 0; i < 8; ++i) *(float4*)&op[i * 4] = z;
  } else {
    const ushort* xr = xg1 + ((size_t)bt * NN + rk) * FF + fb;
    float f[32];
    #pragma unroll
    for (int i = 0; i < 4; ++i) {
      uint4 u = *(const uint4*)&xr[i * 8];
      const uint* pu = (const uint*)&u;
      #pragma unroll
      for (int e = 0; e < 4; ++e) {
        f[i * 8 + e * 2]     = bf2f((ushort)(pu[e] & 0xffffu));
        f[i * 8 + e * 2 + 1] = bf2f((ushort)(pu[e] >> 16));
      }
    }
    float sum = 0.f, sq = 0.f;
    #pragma unroll
    for (int i = 0; i < 32; ++i) { sum += f[i]; sq = fmaf(f[i], f[i], sq); }
    sum += __shfl_xor(sum, 1); sq += __shfl_xor(sq, 1);
    sum += __shfl_xor(sum, 2); sq += __shfl_xor(sq, 2);
    const float mu = sum * (1.f / FF);
    const float var = sq * (1.f / FF) - mu * mu;
    const float rstd = rsqrtf(var + 1e-5f);
    #pragma unroll
    for (int i = 0; i < 8; ++i) {
      float4 g = *(const float4*)&gam[fb + i * 4];
      float4 bb = *(const float4*)&bet[fb + i * 4];
      float4 o;
      o.x = (f[i * 4]     - mu) * rstd * g.x + bb.x;
      o.y = (f[i * 4 + 1] - mu) * rstd * g.y + bb.y;
      o.z = (f[i * 4 + 2] - mu) * rstd * g.z + bb.z;
      o.w = (f[i * 4 + 3] - mu) * rstd * g.w + bb.w;
      *(float4*)&op[i * 4] = o;
    }
  }
}

extern "C" void kernel_launch(void* const* d_in, const int* in_sizes, int n_in,
                              void* d_out, int out_size, void* d_ws, size_t ws_size,
                              hipStream_t stream) {
  const float* xin   = (const float*)d_in[0];
  const int*   mask  = (const int*)d_in[1];
  const float* W0    = (const float*)d_in[2];
  const float* a0    = (const float*)d_in[3];
  const float* W1    = (const float*)d_in[4];
  const float* a1    = (const float*)d_in[5];
  const float* gamma = (const float*)d_in[6];
  const float* beta  = (const float*)d_in[7];

  ushort* xg0     = (ushort*)d_ws;                       // 8.39 MB compact bf16
  ushort* xg1     = xg0 + (size_t)BT * NN * FF;          // 8.39 MB compact bf16
  int*    rrank_g = (int*)(xg1 + (size_t)BT * NN * FF);  // 131 KB

  layer_kernel<true><<<BT * HH, 512, 0, stream>>>(xin, nullptr, mask, W0, a0, xg0, rrank_g);
  layer_kernel<false><<<BT * HH, 512, 0, stream>>>(nullptr, xg0, mask, W1, a1, xg1, nullptr);
  ln_scatter<<<BT * 4, 256, 0, stream>>>(xg1, rrank_g, gamma, beta, (float*)d_out);
}